// Round 8
// baseline (1021.864 us; speedup 1.0000x reference)
//
#include <hip/hip_runtime.h>
#include <math.h>

// H[i,j] = max_k ( |W[i,k]| + |W[j,k]| ), W: 2048 x 10000 fp32.
// Round 8: break the LDS-delivery wall (round 7 measured serial VALU+LDS sum:
// both pipes ~6150 cyc/block-step). New operand routing:
//   - WT[k][i] = |W[i][k]| precomputed in d_ws (82 MB, rebuilt every call).
//   - A-tile staged LDS from WT with b128 writes (k-major, no scatter).
//   - B-fragments read DIRECT from WT global (L1/L3), double-buffered depth-1.
//   LDS now carries only A (~43 B/cyc/CU = 50% of ceiling), vmem carries B
//   (~43 B/cyc L1-return) -> VALU is the only saturated pipe (~6144 cyc/step).
//   - inner loop as float2 adds (v_pk_add_f32 if codegen cooperates) + v_max3.
//   - k-clamp to K-1 instead of zero-pad: re-reading a legal k is a no-op
//     under max -> no zero logic, consistent A/B by construction.
// Fallback to the proven round-7 kernel if ws_size < 82 MB.

constexpr int N  = 2048;
constexpr int K  = 10000;
constexpr int BT = 128;                  // output tile dim
constexpr int BK = 32;                   // k per step
constexpr int NT = N / BT;               // 16
constexpr int NTRI = NT * (NT + 1) / 2;  // 136 upper-tri tiles
constexpr int TILES8 = 72;               // tiles with 8 K-splits
constexpr int BID8 = TILES8 * 8;         // 576
constexpr int CH8 = 1252;                // per-split span (mult of 4)
constexpr int CH7 = 1432;
constexpr int NS8 = 40;                  // ceil(1252/32)
constexpr int NS7 = 45;                  // ceil(1432/32)
constexpr size_t WT_BYTES = (size_t)K * N * sizeof(float);  // 81,920,000

typedef float f32x2 __attribute__((ext_vector_type(2)));

__device__ __forceinline__ float max3f(float a, float b, float c) {
    float d;
    asm("v_max3_f32 %0, %1, %2, %3" : "=v"(d) : "v"(a), "v"(b), "v"(c));
    return d;
}

__global__ void zero_out_kernel(float4* __restrict__ p, int n4) {
    const int i = blockIdx.x * blockDim.x + threadIdx.x;
    if (i < n4) p[i] = make_float4(0.f, 0.f, 0.f, 0.f);
}

// WT[k][i] = |W[i][k]|  (64x64 LDS tiles, coalesced both sides)
__global__ __launch_bounds__(256)
void transpose_abs_kernel(const float* __restrict__ W, float* __restrict__ WT) {
    __shared__ float S[64][65];
    const int i0 = blockIdx.x * 64;
    const int k0 = blockIdx.y * 64;
    const int tid = threadIdx.x;
#pragma unroll
    for (int w = 0; w < 16; ++w) {
        const int idx = w * 256 + tid;
        const int r = idx >> 6, c = idx & 63;
        if (k0 + c < K) S[r][c] = fabsf(W[(size_t)(i0 + r) * K + k0 + c]);
    }
    __syncthreads();
#pragma unroll
    for (int w = 0; w < 16; ++w) {
        const int idx = w * 256 + tid;
        const int r = idx >> 6, c = idx & 63;
        if (k0 + r < K) WT[(size_t)(k0 + r) * N + i0 + c] = S[c][r];
    }
}

// ---------------- main gram kernel (WT path) ----------------
__global__ __launch_bounds__(256, 3)
void gram_wt_kernel(const float* __restrict__ WT, float* __restrict__ H) {
    __shared__ float As[BK][BT];         // k-major A tile only (16 KB)

    const int tid = threadIdx.x;

    // block decode: (tile, split-chunk), 72x8 + 64x7 = 1024 blocks
    const int bid = blockIdx.x;
    int tile, kbeg, nstep;
    if (bid < BID8) {
        tile  = bid >> 3;
        kbeg  = (bid & 7) * CH8;
        nstep = NS8;
    } else {
        const int r = bid - BID8;
        tile  = TILES8 + r / 7;
        kbeg  = (r % 7) * CH7;
        nstep = NS7;
    }
    int t = tile;
    int bi = 0;
    while (t >= NT - bi) { t -= NT - bi; ++bi; }
    const int bj = bi + t;
    const int i0 = bi * BT, j0 = bj * BT;

    // staging map: thread loads 16 consecutive floats of one k-row of the A tile
    const int skk  = tid >> 3;           // 0..31
    const int soff = (tid & 7) * 16;     // 0..112

    // compute map: four 4x4 sub-tiles at (+0,+64)
    const int tx = tid & 15, ty = tid >> 4;
    const int ra = ty * 4, rb = ra + 64;
    const int ca = tx * 4, cb = ca + 64;

    float acc[8][8];
#pragma unroll
    for (int m = 0; m < 8; ++m)
#pragma unroll
        for (int n = 0; n < 8; ++n) acc[m][n] = 0.0f;   // all sums >= 0

    // A staging prefetch (step s+1 issued under compute of step s)
    float4 va[4];
    auto fetchA = [&](int s) {
        int kg = kbeg + s * BK + skk;
        if (kg > K - 1) kg = K - 1;      // clamp: legal duplicate k under max
        const float* src = WT + (size_t)kg * N + i0 + soff;
#pragma unroll
        for (int q = 0; q < 4; ++q)
            va[q] = *reinterpret_cast<const float4*>(src + q * 4);
    };

    // B double-buffer direct from WT (depth-1 pipeline, static indexing)
    const float* bAp = WT + j0 + ca;
    const float* bBp = WT + j0 + cb;
    float4 b[2][4];
    auto fetchB = [&](int buf, int kg) {
        int k0c = kg     > K - 1 ? K - 1 : kg;
        int k1c = kg + 1 > K - 1 ? K - 1 : kg + 1;
        b[buf][0] = *reinterpret_cast<const float4*>(bAp + (size_t)k0c * N);
        b[buf][1] = *reinterpret_cast<const float4*>(bBp + (size_t)k0c * N);
        b[buf][2] = *reinterpret_cast<const float4*>(bAp + (size_t)k1c * N);
        b[buf][3] = *reinterpret_cast<const float4*>(bBp + (size_t)k1c * N);
    };

    fetchA(0);
    fetchB(0, kbeg);

    for (int s = 0; s < nstep; ++s) {
        __syncthreads();                 // previous compute done with As
#pragma unroll
        for (int q = 0; q < 4; ++q)      // b128 writes, contiguous (no scatter)
            *reinterpret_cast<float4*>(&As[skk][soff + q * 4]) = va[q];
        if (s + 1 < nstep) fetchA(s + 1);
        __syncthreads();                 // As ready

        const int kgs = kbeg + s * BK;
#pragma unroll
        for (int p = 0; p < 16; ++p) {   // 16 k-pairs per step
            fetchB((p + 1) & 1, kgs + 2 * p + 2);   // prefetch next pair
            const int kk = 2 * p;
            // A fragments: 16-lane broadcast reads, conflict-free
            const float4 A0a = *reinterpret_cast<const float4*>(&As[kk][ra]);
            const float4 A0b = *reinterpret_cast<const float4*>(&As[kk][rb]);
            const float4 A1a = *reinterpret_cast<const float4*>(&As[kk + 1][ra]);
            const float4 A1b = *reinterpret_cast<const float4*>(&As[kk + 1][rb]);
            const float a0[8] = {A0a.x, A0a.y, A0a.z, A0a.w, A0b.x, A0b.y, A0b.z, A0b.w};
            const float a1[8] = {A1a.x, A1a.y, A1a.z, A1a.w, A1b.x, A1b.y, A1b.z, A1b.w};
            const float4 c0 = b[p & 1][0], c1 = b[p & 1][1];
            const float4 c2 = b[p & 1][2], c3 = b[p & 1][3];
            const f32x2 b0[4] = {{c0.x, c0.y}, {c0.z, c0.w}, {c1.x, c1.y}, {c1.z, c1.w}};
            const f32x2 b1[4] = {{c2.x, c2.y}, {c2.z, c2.w}, {c3.x, c3.y}, {c3.z, c3.w}};
#pragma unroll
            for (int m = 0; m < 8; ++m) {
                const f32x2 am0 = {a0[m], a0[m]};
                const f32x2 am1 = {a1[m], a1[m]};
#pragma unroll
                for (int np = 0; np < 4; ++np) {
                    const f32x2 t0 = am0 + b0[np];      // hope: v_pk_add_f32
                    const f32x2 t1 = am1 + b1[np];
                    acc[m][2 * np]     = max3f(acc[m][2 * np],     t0.x, t1.x);
                    acc[m][2 * np + 1] = max3f(acc[m][2 * np + 1], t0.y, t1.y);
                }
            }
        }
    }

    // epilogue: canonical orientation; int-bitcast atomicMax merges K-splits
    int* Hi = (int*)H;
#pragma unroll
    for (int m = 0; m < 8; ++m) {
        const int r = (m < 4) ? (ra + m) : (rb + m - 4);
#pragma unroll
        for (int n = 0; n < 8; ++n) {
            const int c = (n < 4) ? (ca + n) : (cb + n - 4);
            atomicMax(&Hi[(size_t)(i0 + r) * N + j0 + c], __float_as_int(acc[m][n]));
        }
    }
}

// ---------------- fallback (round-7 proven path, used if ws too small) ----
__global__ __launch_bounds__(256, 2)
void tropical_gram_kernel(const float* __restrict__ W, float* __restrict__ H) {
    __shared__ float As[BK][BT];
    __shared__ float Bs[BK][BT];
    const int tid = threadIdx.x;
    const int bid = blockIdx.x;
    int tile, kbeg, nstep;
    if (bid < BID8) { tile = bid >> 3; kbeg = (bid & 7) * CH8; nstep = NS8; }
    else { const int r = bid - BID8; tile = TILES8 + r / 7; kbeg = (r % 7) * CH7; nstep = NS7; }
    int t = tile; int bi = 0;
    while (t >= NT - bi) { t -= NT - bi; ++bi; }
    const int bj = bi + t;
    const int i0 = bi * BT, j0 = bj * BT;
    const bool diag = (bi == bj);
    const int srow = tid & 127, kh = tid >> 7;
    const float* rowi = W + (size_t)(i0 + srow) * K + kbeg + kh * 16;
    const float* rowj = W + (size_t)(j0 + srow) * K + kbeg + kh * 16;
    const int tx = tid & 15, ty = tid >> 4;
    const int ra = ty * 4, rb = ra + 64, ca = tx * 4, cb = ca + 64;
    float acc[8][8];
#pragma unroll
    for (int m = 0; m < 8; ++m)
#pragma unroll
        for (int n = 0; n < 8; ++n) acc[m][n] = 0.0f;
    float4 va[4], vb[4];
    const float4 z4 = make_float4(0.f, 0.f, 0.f, 0.f);
    auto fetchA = [&](int s) {
#pragma unroll
        for (int qq = 0; qq < 4; ++qq) {
            const int kg = kbeg + kh * 16 + s * BK + qq * 4;
            va[qq] = (kg < K) ? *reinterpret_cast<const float4*>(rowi + s * BK + qq * 4) : z4;
        }
    };
    auto fetchB = [&](int s) {
#pragma unroll
        for (int qq = 0; qq < 4; ++qq) {
            const int kg = kbeg + kh * 16 + s * BK + qq * 4;
            vb[qq] = (kg < K) ? *reinterpret_cast<const float4*>(rowj + s * BK + qq * 4) : z4;
        }
    };
    fetchA(0);
    if (!diag) fetchB(0);
    const float (*Bsrc)[BT] = diag ? As : Bs;
    for (int s = 0; s < nstep; ++s) {
        __syncthreads();
#pragma unroll
        for (int qq = 0; qq < 4; ++qq) {
            const int kb = kh * 16 + qq * 4;
            As[kb + 0][srow] = fabsf(va[qq].x);
            As[kb + 1][srow] = fabsf(va[qq].y);
            As[kb + 2][srow] = fabsf(va[qq].z);
            As[kb + 3][srow] = fabsf(va[qq].w);
        }
        if (!diag) {
#pragma unroll
            for (int qq = 0; qq < 4; ++qq) {
                const int kb = kh * 16 + qq * 4;
                Bs[kb + 0][srow] = fabsf(vb[qq].x);
                Bs[kb + 1][srow] = fabsf(vb[qq].y);
                Bs[kb + 2][srow] = fabsf(vb[qq].z);
                Bs[kb + 3][srow] = fabsf(vb[qq].w);
            }
        }
        if (s + 1 < nstep) { fetchA(s + 1); if (!diag) fetchB(s + 1); }
        __syncthreads();
#pragma unroll 2
        for (int kk = 0; kk < BK; kk += 2) {
            const float4 A0a = *reinterpret_cast<const float4*>(&As[kk][ra]);
            const float4 A0b = *reinterpret_cast<const float4*>(&As[kk][rb]);
            const float4 A1a = *reinterpret_cast<const float4*>(&As[kk + 1][ra]);
            const float4 A1b = *reinterpret_cast<const float4*>(&As[kk + 1][rb]);
            const float4 B0a = *reinterpret_cast<const float4*>(&Bsrc[kk][ca]);
            const float4 B0b = *reinterpret_cast<const float4*>(&Bsrc[kk][cb]);
            const float4 B1a = *reinterpret_cast<const float4*>(&Bsrc[kk + 1][ca]);
            const float4 B1b = *reinterpret_cast<const float4*>(&Bsrc[kk + 1][cb]);
            const float a0[8] = {A0a.x, A0a.y, A0a.z, A0a.w, A0b.x, A0b.y, A0b.z, A0b.w};
            const float a1[8] = {A1a.x, A1a.y, A1a.z, A1a.w, A1b.x, A1b.y, A1b.z, A1b.w};
            const float b0[8] = {B0a.x, B0a.y, B0a.z, B0a.w, B0b.x, B0b.y, B0b.z, B0b.w};
            const float b1[8] = {B1a.x, B1a.y, B1a.z, B1a.w, B1b.x, B1b.y, B1b.z, B1b.w};
#pragma unroll
            for (int m = 0; m < 8; ++m)
#pragma unroll
                for (int n = 0; n < 8; ++n)
                    acc[m][n] = max3f(acc[m][n], a0[m] + b0[n], a1[m] + b1[n]);
        }
    }
    int* Hi = (int*)H;
#pragma unroll
    for (int m = 0; m < 8; ++m) {
        const int r = (m < 4) ? (ra + m) : (rb + m - 4);
#pragma unroll
        for (int n = 0; n < 8; ++n) {
            const int c = (n < 4) ? (ca + n) : (cb + n - 4);
            atomicMax(&Hi[(size_t)(i0 + r) * N + j0 + c], __float_as_int(acc[m][n]));
        }
    }
}

// mirror: H[j][i] = H[i][j] for strictly-lower 64-tiles
constexpr int MT = 64;
constexpr int NT64 = N / MT;                 // 32
constexpr int NMIR = NT64 * (NT64 - 1) / 2;  // 496

__global__ __launch_bounds__(256)
void mirror_kernel(float* __restrict__ H) {
    __shared__ float S[MT][MT + 1];
    int t = blockIdx.x;
    int ti = 0;
    while (t >= NT64 - 1 - ti) { t -= NT64 - 1 - ti; ++ti; }
    const int tj = ti + 1 + t;
    const int r0 = ti * MT, c0 = tj * MT;
    const int tid = threadIdx.x;
#pragma unroll
    for (int w = 0; w < 16; ++w) {
        const int idx = w * 256 + tid;
        const int r = idx >> 6, c = idx & 63;
        S[r][c] = H[(size_t)(r0 + r) * N + c0 + c];
    }
    __syncthreads();
#pragma unroll
    for (int w = 0; w < 16; ++w) {
        const int idx = w * 256 + tid;
        const int r = idx >> 6, c = idx & 63;
        H[(size_t)(c0 + r) * N + r0 + c] = S[c][r];
    }
}

extern "C" void kernel_launch(void* const* d_in, const int* in_sizes, int n_in,
                              void* d_out, int out_size, void* d_ws, size_t ws_size,
                              hipStream_t stream) {
    const float* W = (const float*)d_in[0];
    float* H = (float*)d_out;
    (void)in_sizes; (void)n_in; (void)out_size;

    const int n4 = N * N / 4;
    zero_out_kernel<<<(n4 + 255) / 256, 256, 0, stream>>>((float4*)H, n4);

    if (ws_size >= WT_BYTES) {
        float* WT = (float*)d_ws;
        transpose_abs_kernel<<<dim3(N / 64, (K + 63) / 64), dim3(256), 0, stream>>>(W, WT);
        gram_wt_kernel<<<dim3(1024), dim3(256), 0, stream>>>(WT, H);
    } else {
        tropical_gram_kernel<<<dim3(1024), dim3(256), 0, stream>>>(W, H);
    }
    mirror_kernel<<<dim3(NMIR), dim3(256), 0, stream>>>(H);
}

// Round 10
// 1013.208 us; speedup vs baseline: 1.0085x; 1.0085x over previous
//
#include <hip/hip_runtime.h>
#include <math.h>

// H[i,j] = max_k ( |W[i,k]| + |W[j,k]| ), W: 2048 x 10000 fp32.
// Round 10 = round-9 resubmit (infra failure; never ran). WT-hybrid with the
// three round-8 measured defects fixed:
//  (1) As pitch 128 -> 132 floats: write pattern becomes exactly 8 lanes per
//      bank-quad = the wave64-b128 hardware minimum (was 32 lanes on one
//      quad -> 16.6M conflicts).
//  (2) B global-prefetch depth 1 -> 2 (4 rotating float4[4] buffers, fully
//      unrolled p-loop => static indices), continuous k-stream across steps.
//  (3) __syncthreads -> raw s_barrier / lgkmcnt(0)+s_barrier so the barrier
//      never drains vmcnt: A/B prefetches stay in flight across steps (T4).
//  Inner loop pk-packed (n-adjacent pairs -> v_pk_add_f32 + v_max3_f32).
//  LDS carries A only; B rides vmem/L1; VALU is the intended sole bottleneck.
// Fallback to the proven round-7 kernel if ws_size < 82 MB.

constexpr int N  = 2048;
constexpr int K  = 10000;
constexpr int BT = 128;
constexpr int BK = 32;
constexpr int NT = N / BT;               // 16
constexpr int NTRI = NT * (NT + 1) / 2;  // 136
constexpr int TILES8 = 72;
constexpr int BID8 = TILES8 * 8;         // 576
constexpr int CH8 = 1252;
constexpr int CH7 = 1432;
constexpr int NS8 = 40;
constexpr int NS7 = 45;
constexpr int PAD = 132;                 // As row pitch: 132%4==0 (16B align),
                                         // 132 mod 32 == 4 -> 8 lanes/bank-quad
constexpr size_t WT_BYTES = (size_t)K * N * sizeof(float);

typedef float f32x2 __attribute__((ext_vector_type(2)));

__device__ __forceinline__ float max3f(float a, float b, float c) {
    float d;
    asm("v_max3_f32 %0, %1, %2, %3" : "=v"(d) : "v"(a), "v"(b), "v"(c));
    return d;
}

__global__ void zero_out_kernel(float4* __restrict__ p, int n4) {
    const int i = blockIdx.x * blockDim.x + threadIdx.x;
    if (i < n4) p[i] = make_float4(0.f, 0.f, 0.f, 0.f);
}

// WT[k][i] = |W[i][k]|
__global__ __launch_bounds__(256)
void transpose_abs_kernel(const float* __restrict__ W, float* __restrict__ WT) {
    __shared__ float S[64][65];
    const int i0 = blockIdx.x * 64;
    const int k0 = blockIdx.y * 64;
    const int tid = threadIdx.x;
#pragma unroll
    for (int w = 0; w < 16; ++w) {
        const int idx = w * 256 + tid;
        const int r = idx >> 6, c = idx & 63;
        if (k0 + c < K) S[r][c] = fabsf(W[(size_t)(i0 + r) * K + k0 + c]);
    }
    __syncthreads();
#pragma unroll
    for (int w = 0; w < 16; ++w) {
        const int idx = w * 256 + tid;
        const int r = idx >> 6, c = idx & 63;
        if (k0 + r < K) WT[(size_t)(k0 + r) * N + i0 + c] = S[c][r];
    }
}

// ---------------- main gram kernel (WT hybrid, fixed) ----------------
__global__ __launch_bounds__(256, 2)
void gram_wt_kernel(const float* __restrict__ WT, float* __restrict__ H) {
    __shared__ float As[BK][PAD];        // A tile only, k-major, padded pitch

    const int tid = threadIdx.x;

    const int bid = blockIdx.x;
    int tile, kbeg, nstep;
    if (bid < BID8) {
        tile  = bid >> 3;
        kbeg  = (bid & 7) * CH8;
        nstep = NS8;
    } else {
        const int r = bid - BID8;
        tile  = TILES8 + r / 7;
        kbeg  = (r % 7) * CH7;
        nstep = NS7;
    }
    int t = tile;
    int bi = 0;
    while (t >= NT - bi) { t -= NT - bi; ++bi; }
    const int bj = bi + t;
    const int i0 = bi * BT, j0 = bj * BT;

    // staging map: thread loads/writes 16 consecutive floats of one k-row
    const int skk  = tid >> 3;           // 0..31
    const int soff = (tid & 7) * 16;     // 0..112

    // compute map: four 4x4 sub-tiles at (+0,+64)
    const int tx = tid & 15, ty = tid >> 4;
    const int ra = ty * 4, rb = ra + 64;
    const int ca = tx * 4, cb = ca + 64;

    float acc[8][8];
#pragma unroll
    for (int m = 0; m < 8; ++m)
#pragma unroll
        for (int n = 0; n < 8; ++n) acc[m][n] = 0.0f;

    // A staging prefetch
    float4 va[4];
    auto fetchA = [&](int s) {
        int kg = kbeg + s * BK + skk;
        if (kg > K - 1) kg = K - 1;      // duplicate k is a no-op under max
        const float* src = WT + (size_t)kg * N + i0 + soff;
#pragma unroll
        for (int q = 0; q < 4; ++q)
            va[q] = *reinterpret_cast<const float4*>(src + q * 4);
    };

    // B: depth-2 prefetch, 4 rotating buffers, continuous k-stream
    const float* __restrict__ bAp = WT + j0 + ca;
    const float* __restrict__ bBp = WT + j0 + cb;
    float4 b[4][4];
    auto fetchB = [&](int buf, int kg) {
        const int k0c = kg     > K - 1 ? K - 1 : kg;
        const int k1c = kg + 1 > K - 1 ? K - 1 : kg + 1;
        b[buf][0] = *reinterpret_cast<const float4*>(bAp + (size_t)k0c * N);
        b[buf][1] = *reinterpret_cast<const float4*>(bBp + (size_t)k0c * N);
        b[buf][2] = *reinterpret_cast<const float4*>(bAp + (size_t)k1c * N);
        b[buf][3] = *reinterpret_cast<const float4*>(bBp + (size_t)k1c * N);
    };

    fetchA(0);
    fetchB(0, kbeg);                     // pair 0
    fetchB(1, kbeg + 2);                 // pair 1

    for (int s = 0; s < nstep; ++s) {
        // every wave reaching this point has CONSUMED its As reads (lgkmcnt
        // forced by use) -> raw barrier, no vmcnt drain: prefetches stay live
        asm volatile("s_barrier" ::: "memory");
#pragma unroll
        for (int q = 0; q < 4; ++q)
            *reinterpret_cast<float4*>(&As[skk][soff + q * 4]) = va[q];
        if (s + 1 < nstep) fetchA(s + 1);
        // publish LDS writes; still no vmcnt drain
        asm volatile("s_waitcnt lgkmcnt(0)\n\ts_barrier" ::: "memory");

        const int kgs = kbeg + s * BK;
#pragma unroll
        for (int p = 0; p < 16; ++p) {
            // prefetch pair p+2 (rolls into next step's k automatically)
            fetchB((p + 2) & 3, kgs + 2 * p + 4);

            const int kk = 2 * p;
            const float4 A0a = *reinterpret_cast<const float4*>(&As[kk][ra]);
            const float4 A0b = *reinterpret_cast<const float4*>(&As[kk][rb]);
            const float4 A1a = *reinterpret_cast<const float4*>(&As[kk + 1][ra]);
            const float4 A1b = *reinterpret_cast<const float4*>(&As[kk + 1][rb]);
            const float a0[8] = {A0a.x, A0a.y, A0a.z, A0a.w, A0b.x, A0b.y, A0b.z, A0b.w};
            const float a1[8] = {A1a.x, A1a.y, A1a.z, A1a.w, A1b.x, A1b.y, A1b.z, A1b.w};
            const float4 c0 = b[p & 3][0], c1 = b[p & 3][1];
            const float4 c2 = b[p & 3][2], c3 = b[p & 3][3];
            const f32x2 b0p[4] = {{c0.x, c0.y}, {c0.z, c0.w}, {c1.x, c1.y}, {c1.z, c1.w}};
            const f32x2 b1p[4] = {{c2.x, c2.y}, {c2.z, c2.w}, {c3.x, c3.y}, {c3.z, c3.w}};
#pragma unroll
            for (int m = 0; m < 8; ++m) {
                const f32x2 am0 = {a0[m], a0[m]};
                const f32x2 am1 = {a1[m], a1[m]};
#pragma unroll
                for (int np = 0; np < 4; ++np) {
                    const f32x2 t0 = am0 + b0p[np];     // v_pk_add_f32
                    const f32x2 t1 = am1 + b1p[np];
                    acc[m][2 * np]     = max3f(acc[m][2 * np],     t0.x, t1.x);
                    acc[m][2 * np + 1] = max3f(acc[m][2 * np + 1], t0.y, t1.y);
                }
            }
        }
    }

    int* Hi = (int*)H;
#pragma unroll
    for (int m = 0; m < 8; ++m) {
        const int r = (m < 4) ? (ra + m) : (rb + m - 4);
#pragma unroll
        for (int n = 0; n < 8; ++n) {
            const int c = (n < 4) ? (ca + n) : (cb + n - 4);
            atomicMax(&Hi[(size_t)(i0 + r) * N + j0 + c], __float_as_int(acc[m][n]));
        }
    }
}

// ---------------- fallback (round-7 proven path) ----------------
__global__ __launch_bounds__(256, 2)
void tropical_gram_kernel(const float* __restrict__ W, float* __restrict__ H) {
    __shared__ float As[BK][BT];
    __shared__ float Bs[BK][BT];
    const int tid = threadIdx.x;
    const int bid = blockIdx.x;
    int tile, kbeg, nstep;
    if (bid < BID8) { tile = bid >> 3; kbeg = (bid & 7) * CH8; nstep = NS8; }
    else { const int r = bid - BID8; tile = TILES8 + r / 7; kbeg = (r % 7) * CH7; nstep = NS7; }
    int t = tile; int bi = 0;
    while (t >= NT - bi) { t -= NT - bi; ++bi; }
    const int bj = bi + t;
    const int i0 = bi * BT, j0 = bj * BT;
    const bool diag = (bi == bj);
    const int srow = tid & 127, kh = tid >> 7;
    const float* rowi = W + (size_t)(i0 + srow) * K + kbeg + kh * 16;
    const float* rowj = W + (size_t)(j0 + srow) * K + kbeg + kh * 16;
    const int tx = tid & 15, ty = tid >> 4;
    const int ra = ty * 4, rb = ra + 64, ca = tx * 4, cb = ca + 64;
    float acc[8][8];
#pragma unroll
    for (int m = 0; m < 8; ++m)
#pragma unroll
        for (int n = 0; n < 8; ++n) acc[m][n] = 0.0f;
    float4 va[4], vb[4];
    const float4 z4 = make_float4(0.f, 0.f, 0.f, 0.f);
    auto fetchA = [&](int s) {
#pragma unroll
        for (int qq = 0; qq < 4; ++qq) {
            const int kg = kbeg + kh * 16 + s * BK + qq * 4;
            va[qq] = (kg < K) ? *reinterpret_cast<const float4*>(rowi + s * BK + qq * 4) : z4;
        }
    };
    auto fetchB = [&](int s) {
#pragma unroll
        for (int qq = 0; qq < 4; ++qq) {
            const int kg = kbeg + kh * 16 + s * BK + qq * 4;
            vb[qq] = (kg < K) ? *reinterpret_cast<const float4*>(rowj + s * BK + qq * 4) : z4;
        }
    };
    fetchA(0);
    if (!diag) fetchB(0);
    const float (*Bsrc)[BT] = diag ? As : Bs;
    for (int s = 0; s < nstep; ++s) {
        __syncthreads();
#pragma unroll
        for (int qq = 0; qq < 4; ++qq) {
            const int kb = kh * 16 + qq * 4;
            As[kb + 0][srow] = fabsf(va[qq].x);
            As[kb + 1][srow] = fabsf(va[qq].y);
            As[kb + 2][srow] = fabsf(va[qq].z);
            As[kb + 3][srow] = fabsf(va[qq].w);
        }
        if (!diag) {
#pragma unroll
            for (int qq = 0; qq < 4; ++qq) {
                const int kb = kh * 16 + qq * 4;
                Bs[kb + 0][srow] = fabsf(vb[qq].x);
                Bs[kb + 1][srow] = fabsf(vb[qq].y);
                Bs[kb + 2][srow] = fabsf(vb[qq].z);
                Bs[kb + 3][srow] = fabsf(vb[qq].w);
            }
        }
        if (s + 1 < nstep) { fetchA(s + 1); if (!diag) fetchB(s + 1); }
        __syncthreads();
#pragma unroll 2
        for (int kk = 0; kk < BK; kk += 2) {
            const float4 A0a = *reinterpret_cast<const float4*>(&As[kk][ra]);
            const float4 A0b = *reinterpret_cast<const float4*>(&As[kk][rb]);
            const float4 A1a = *reinterpret_cast<const float4*>(&As[kk + 1][ra]);
            const float4 A1b = *reinterpret_cast<const float4*>(&As[kk + 1][rb]);
            const float4 B0a = *reinterpret_cast<const float4*>(&Bsrc[kk][ca]);
            const float4 B0b = *reinterpret_cast<const float4*>(&Bsrc[kk][cb]);
            const float4 B1a = *reinterpret_cast<const float4*>(&Bsrc[kk + 1][ca]);
            const float4 B1b = *reinterpret_cast<const float4*>(&Bsrc[kk + 1][cb]);
            const float a0[8] = {A0a.x, A0a.y, A0a.z, A0a.w, A0b.x, A0b.y, A0b.z, A0b.w};
            const float a1[8] = {A1a.x, A1a.y, A1a.z, A1a.w, A1b.x, A1b.y, A1b.z, A1b.w};
            const float b0[8] = {B0a.x, B0a.y, B0a.z, B0a.w, B0b.x, B0b.y, B0b.z, B0b.w};
            const float b1[8] = {B1a.x, B1a.y, B1a.z, B1a.w, B1b.x, B1b.y, B1b.z, B1b.w};
#pragma unroll
            for (int m = 0; m < 8; ++m)
#pragma unroll
                for (int n = 0; n < 8; ++n)
                    acc[m][n] = max3f(acc[m][n], a0[m] + b0[n], a1[m] + b1[n]);
        }
    }
    int* Hi = (int*)H;
#pragma unroll
    for (int m = 0; m < 8; ++m) {
        const int r = (m < 4) ? (ra + m) : (rb + m - 4);
#pragma unroll
        for (int n = 0; n < 8; ++n) {
            const int c = (n < 4) ? (ca + n) : (cb + n - 4);
            atomicMax(&Hi[(size_t)(i0 + r) * N + j0 + c], __float_as_int(acc[m][n]));
        }
    }
}

// mirror: H[j][i] = H[i][j] for strictly-lower 64-tiles
constexpr int MT = 64;
constexpr int NT64 = N / MT;
constexpr int NMIR = NT64 * (NT64 - 1) / 2;

__global__ __launch_bounds__(256)
void mirror_kernel(float* __restrict__ H) {
    __shared__ float S[MT][MT + 1];
    int t = blockIdx.x;
    int ti = 0;
    while (t >= NT64 - 1 - ti) { t -= NT64 - 1 - ti; ++ti; }
    const int tj = ti + 1 + t;
    const int r0 = ti * MT, c0 = tj * MT;
    const int tid = threadIdx.x;
#pragma unroll
    for (int w = 0; w < 16; ++w) {
        const int idx = w * 256 + tid;
        const int r = idx >> 6, c = idx & 63;
        S[r][c] = H[(size_t)(r0 + r) * N + c0 + c];
    }
    __syncthreads();
#pragma unroll
    for (int w = 0; w < 16; ++w) {
        const int idx = w * 256 + tid;
        const int r = idx >> 6, c = idx & 63;
        H[(size_t)(c0 + r) * N + r0 + c] = S[c][r];
    }
}

extern "C" void kernel_launch(void* const* d_in, const int* in_sizes, int n_in,
                              void* d_out, int out_size, void* d_ws, size_t ws_size,
                              hipStream_t stream) {
    const float* W = (const float*)d_in[0];
    float* H = (float*)d_out;
    (void)in_sizes; (void)n_in; (void)out_size;

    const int n4 = N * N / 4;
    zero_out_kernel<<<(n4 + 255) / 256, 256, 0, stream>>>((float4*)H, n4);

    if (ws_size >= WT_BYTES) {
        float* WT = (float*)d_ws;
        transpose_abs_kernel<<<dim3(N / 64, (K + 63) / 64), dim3(256), 0, stream>>>(W, WT);
        gram_wt_kernel<<<dim3(1024), dim3(256), 0, stream>>>(WT, H);
    } else {
        tropical_gram_kernel<<<dim3(1024), dim3(256), 0, stream>>>(W, H);
    }
    mirror_kernel<<<dim3(NMIR), dim3(256), 0, stream>>>(H);
}

// Round 12
// 946.089 us; speedup vs baseline: 1.0801x; 1.0709x over previous
//
#include <hip/hip_runtime.h>
#include <math.h>

// H[i,j] = max_k ( |W[i,k]| + |W[j,k]| ), W: 2048 x 10000 fp32 (values >= 0).
// Round 12 = round-11 resubmit (infra failure; never ran). Best-known
// both-LDS family (R6/R7, 924-985us) + three proven or clean upgrades:
//  (a) 5 blocks/CU: grid 1280 = 56 tiles x 10 splits + 80 tiles x 9 splits,
//      LDS 5 x 32KB = exactly 160KB/CU, VGPR ~70-90 naturally <= 102 (no
//      launch_bounds squeeze -> no R5/R6 spill trap).
//  (b) pk-packed inner loop from R10 (correctness-proven): v_pk_add_f32 +
//      v_max3_f32, 2048 vs 3072 VALU instr/thread/step.
//  (c) raw s_barrier / lgkmcnt(0)+s_barrier from R10: no vmcnt drain at the
//      step boundary, global prefetches stay in flight across steps.
// Canonical-orientation atomics + mirror kernel (proven R5+).

constexpr int N  = 2048;
constexpr int K  = 10000;
constexpr int BT = 128;
constexpr int BK = 32;
constexpr int NT = N / BT;                // 16
constexpr int NTRI = NT * (NT + 1) / 2;   // 136 upper-tri tiles
constexpr int TILES10 = 56;               // tiles with 10 K-splits
constexpr int BID10 = TILES10 * 10;       // 560
constexpr int CH10 = 1000;                // 10*1000 = 10000 exact (mult of 4)
constexpr int CH9  = 1112;                // 9*1112 = 10008 >= 10000 (mult of 4)
constexpr int NS10 = 32;                  // 32*32=1024 covers 1000 (tail guarded)
constexpr int NS9  = 35;                  // 35*32=1120 covers 1112 (tail guarded)
// grid = 560 + 80*9 = 1280 blocks = 5 blocks/CU x 256 CU

typedef float f32x2 __attribute__((ext_vector_type(2)));

__device__ __forceinline__ float max3f(float a, float b, float c) {
    float d;
    asm("v_max3_f32 %0, %1, %2, %3" : "=v"(d) : "v"(a), "v"(b), "v"(c));
    return d;
}

__global__ void zero_out_kernel(float4* __restrict__ p, int n4) {
    const int i = blockIdx.x * blockDim.x + threadIdx.x;
    if (i < n4) p[i] = make_float4(0.f, 0.f, 0.f, 0.f);
}

__global__ __launch_bounds__(256, 2)
void tropical_gram_kernel(const float* __restrict__ W, float* __restrict__ H) {
    __shared__ float As[BK][BT];   // k-major: As[k][row], 16 KB
    __shared__ float Bs[BK][BT];   // 16 KB -> 32 KB/block, 5 blocks/CU

    const int tid = threadIdx.x;

    // ---- block decode: (tile, split-chunk), 56x10 + 80x9 = 1280
    const int bid = blockIdx.x;
    int tile, kbeg, nstep;
    if (bid < BID10) {
        tile  = bid / 10;
        kbeg  = (bid % 10) * CH10;
        nstep = NS10;
    } else {
        const int r = bid - BID10;
        tile  = TILES10 + r / 9;
        kbeg  = (r % 9) * CH9;
        nstep = NS9;
    }
    int t = tile;
    int bi = 0;
    while (t >= NT - bi) { t -= NT - bi; ++bi; }
    const int bj = bi + t;
    const int i0 = bi * BT, j0 = bj * BT;
    const bool diag = (bi == bj);

    // ---- staging map: thread stages 16 consecutive k of one row/side
    const int srow = tid & 127;          // row within tile
    const int kh   = tid >> 7;           // 0/1: which 16-k half (wave-uniform)
    const float* rowi = W + (size_t)(i0 + srow) * K + kbeg + kh * 16;
    const float* rowj = W + (size_t)(j0 + srow) * K + kbeg + kh * 16;

    // ---- compute map: four 4x4 sub-tiles at (+0,+64)
    const int tx = tid & 15, ty = tid >> 4;
    const int ra = ty * 4, rb = ra + 64;
    const int ca = tx * 4, cb = ca + 64;

    float acc[8][8];
#pragma unroll
    for (int m = 0; m < 8; ++m)
#pragma unroll
        for (int n = 0; n < 8; ++n) acc[m][n] = 0.0f;   // all sums >= 0

    // ---- global->reg prefetch (issue early, LDS-write late)
    float4 va[4], vb[4];
    const float4 z4 = make_float4(0.f, 0.f, 0.f, 0.f);
    auto fetchA = [&](int s) {
#pragma unroll
        for (int qq = 0; qq < 4; ++qq) {
            const int kg = kbeg + kh * 16 + s * BK + qq * 4;
            va[qq] = (kg < K) ? *reinterpret_cast<const float4*>(rowi + s * BK + qq * 4) : z4;
        }
    };
    auto fetchB = [&](int s) {
#pragma unroll
        for (int qq = 0; qq < 4; ++qq) {
            const int kg = kbeg + kh * 16 + s * BK + qq * 4;
            vb[qq] = (kg < K) ? *reinterpret_cast<const float4*>(rowj + s * BK + qq * 4) : z4;
        }
    };

    fetchA(0);
    if (!diag) fetchB(0);

    // diagonal blocks read B fragments from As (half the staging)
    const float (*Bsrc)[BT] = diag ? As : Bs;

    for (int s = 0; s < nstep; ++s) {
        // every wave here has CONSUMED its As/Bs reads of step s-1 (values fed
        // the adds; compiler-forced lgkmcnt before use) -> raw barrier, NO
        // vmcnt drain: the s+1 global prefetch stays in flight through compute.
        asm volatile("s_barrier" ::: "memory");
#pragma unroll
        for (int qq = 0; qq < 4; ++qq) {
            const int kb = kh * 16 + qq * 4;
            As[kb + 0][srow] = fabsf(va[qq].x);
            As[kb + 1][srow] = fabsf(va[qq].y);
            As[kb + 2][srow] = fabsf(va[qq].z);
            As[kb + 3][srow] = fabsf(va[qq].w);
        }
        if (!diag) {
#pragma unroll
            for (int qq = 0; qq < 4; ++qq) {
                const int kb = kh * 16 + qq * 4;
                Bs[kb + 0][srow] = fabsf(vb[qq].x);
                Bs[kb + 1][srow] = fabsf(vb[qq].y);
                Bs[kb + 2][srow] = fabsf(vb[qq].z);
                Bs[kb + 3][srow] = fabsf(vb[qq].w);
            }
        }
        if (s + 1 < nstep) {             // issue next-step loads under compute
            fetchA(s + 1);
            if (!diag) fetchB(s + 1);
        }
        // publish LDS writes; still no vmcnt drain
        asm volatile("s_waitcnt lgkmcnt(0)\n\ts_barrier" ::: "memory");

#pragma unroll 2
        for (int kk = 0; kk < BK; kk += 2) {
            // A/B fragment reads: stride-16B across lanes -> <=2-way aliasing
            const float4 A0a = *reinterpret_cast<const float4*>(&As[kk][ra]);
            const float4 A0b = *reinterpret_cast<const float4*>(&As[kk][rb]);
            const float4 A1a = *reinterpret_cast<const float4*>(&As[kk + 1][ra]);
            const float4 A1b = *reinterpret_cast<const float4*>(&As[kk + 1][rb]);
            const float4 B0a = *reinterpret_cast<const float4*>(&Bsrc[kk][ca]);
            const float4 B0b = *reinterpret_cast<const float4*>(&Bsrc[kk][cb]);
            const float4 B1a = *reinterpret_cast<const float4*>(&Bsrc[kk + 1][ca]);
            const float4 B1b = *reinterpret_cast<const float4*>(&Bsrc[kk + 1][cb]);
            const float a0[8] = {A0a.x, A0a.y, A0a.z, A0a.w, A0b.x, A0b.y, A0b.z, A0b.w};
            const float a1[8] = {A1a.x, A1a.y, A1a.z, A1a.w, A1b.x, A1b.y, A1b.z, A1b.w};
            const f32x2 b0p[4] = {{B0a.x, B0a.y}, {B0a.z, B0a.w}, {B0b.x, B0b.y}, {B0b.z, B0b.w}};
            const f32x2 b1p[4] = {{B1a.x, B1a.y}, {B1a.z, B1a.w}, {B1b.x, B1b.y}, {B1b.z, B1b.w}};
#pragma unroll
            for (int m = 0; m < 8; ++m) {
                const f32x2 am0 = {a0[m], a0[m]};
                const f32x2 am1 = {a1[m], a1[m]};
#pragma unroll
                for (int np = 0; np < 4; ++np) {
                    const f32x2 t0 = am0 + b0p[np];     // v_pk_add_f32
                    const f32x2 t1 = am1 + b1p[np];
                    acc[m][2 * np]     = max3f(acc[m][2 * np],     t0.x, t1.x);
                    acc[m][2 * np + 1] = max3f(acc[m][2 * np + 1], t0.y, t1.y);
                }
            }
        }
    }

    // ---- epilogue: canonical orientation only; int-bitcast atomicMax merges
    // the K-splits (all values >= 0 -> float order == int order)
    int* Hi = (int*)H;
#pragma unroll
    for (int m = 0; m < 8; ++m) {
        const int r = (m < 4) ? (ra + m) : (rb + m - 4);
#pragma unroll
        for (int n = 0; n < 8; ++n) {
            const int c = (n < 4) ? (ca + n) : (cb + n - 4);
            atomicMax(&Hi[(size_t)(i0 + r) * N + j0 + c], __float_as_int(acc[m][n]));
        }
    }
}

// fill strictly-lower 64-tiles from the upper triangle (H[j][i] = H[i][j])
constexpr int MT = 64;
constexpr int NT64 = N / MT;                 // 32
constexpr int NMIR = NT64 * (NT64 - 1) / 2;  // 496

__global__ __launch_bounds__(256)
void mirror_kernel(float* __restrict__ H) {
    __shared__ float S[MT][MT + 1];
    int t = blockIdx.x;
    int ti = 0;
    while (t >= NT64 - 1 - ti) { t -= NT64 - 1 - ti; ++ti; }
    const int tj = ti + 1 + t;
    const int r0 = ti * MT, c0 = tj * MT;
    const int tid = threadIdx.x;
#pragma unroll
    for (int w = 0; w < 16; ++w) {
        const int idx = w * 256 + tid;
        const int r = idx >> 6, c = idx & 63;
        S[r][c] = H[(size_t)(r0 + r) * N + c0 + c];
    }
    __syncthreads();
#pragma unroll
    for (int w = 0; w < 16; ++w) {
        const int idx = w * 256 + tid;
        const int r = idx >> 6, c = idx & 63;
        H[(size_t)(c0 + r) * N + r0 + c] = S[c][r];
    }
}

extern "C" void kernel_launch(void* const* d_in, const int* in_sizes, int n_in,
                              void* d_out, int out_size, void* d_ws, size_t ws_size,
                              hipStream_t stream) {
    const float* W = (const float*)d_in[0];
    float* H = (float*)d_out;
    (void)in_sizes; (void)n_in; (void)d_ws; (void)ws_size; (void)out_size;

    // zero-init below any result so atomicMax merges cleanly (output is
    // re-poisoned to 0xAA before every timed call -> must zero every call)
    const int n4 = N * N / 4;
    zero_out_kernel<<<(n4 + 255) / 256, 256, 0, stream>>>((float4*)H, n4);
    tropical_gram_kernel<<<dim3(1280), dim3(256), 0, stream>>>(W, H);
    mirror_kernel<<<dim3(NMIR), dim3(256), 0, stream>>>(H);
}

// Round 13
// 921.427 us; speedup vs baseline: 1.1090x; 1.0268x over previous
//
#include <hip/hip_runtime.h>
#include <math.h>

// H[i,j] = max_k ( |W[i,k]| + |W[j,k]| ), W: 2048 x 10000 fp32.
// Round 13: break the phase-lock (R6/R7/R12 all ~950us = serial sum of
// staging + LDS + VALU phases). New structure = T3 2-phase DMA pipeline:
//   - WT[k][i] = |W[i][k]| precomputed in d_ws (R8-proven kernel) makes the
//     k-major LDS tile row-contiguous in global memory.
//   - global_load_lds (width 16) stages A/B tiles directly: no staging regs,
//     no ds_write instructions, no fabsf in the hot loop.
//   - double-buffered LDS, BKD=16: 2 x (8KB+8KB) = 32KB/block, 4 blocks/CU,
//     grid 1024 = exact single round. One __syncthreads() per step (its
//     vmcnt(0) drain IS the DMA-completion wait; next step's DMA was issued
//     before compute and rides under it).
//   - compute inner loop / fragment addressing / pk+max3 / canonical atomics
//     / mirror kernel: R12-verbatim (conflict-free, correctness-proven).
// Tail: per-lane k clamp to K-1; a column holds the SAME k in both tiles by
// construction, so duplicated-k terms are legal under max.
// Fallback to the proven R12 kernel if ws_size < 82 MB.

constexpr int N  = 2048;
constexpr int K  = 10000;
constexpr int BT = 128;
constexpr int BKD = 16;                   // k per step (DMA dbuf path)
constexpr int BK = 32;                    // k per step (fallback path)
constexpr int NT = N / BT;                // 16
constexpr int TILES8 = 72;                // tiles with 8 K-splits
constexpr int BID8 = TILES8 * 8;          // 576
constexpr int CH8 = 1252;                 // per-split span (mult of 4)
constexpr int CH7 = 1432;
constexpr int NSD8 = 79;                  // ceil(1252/16)
constexpr int NSD7 = 90;                  // ceil(1432/16)
constexpr int NS8 = 40;                   // ceil(1252/32) (fallback)
constexpr int NS7 = 45;                   // ceil(1432/32) (fallback)
// grid = 576 + 64*7 = 1024 blocks = 4 blocks/CU x 256 CU

constexpr size_t WT_BYTES = (size_t)K * N * sizeof(float);  // 81,920,000

typedef float f32x2 __attribute__((ext_vector_type(2)));

__device__ __forceinline__ float max3f(float a, float b, float c) {
    float d;
    asm("v_max3_f32 %0, %1, %2, %3" : "=v"(d) : "v"(a), "v"(b), "v"(c));
    return d;
}

__device__ __forceinline__ void gload16(const void* g, void* l) {
    __builtin_amdgcn_global_load_lds(
        (const __attribute__((address_space(1))) void*)g,
        (__attribute__((address_space(3))) void*)l,
        16, 0, 0);
}

__global__ void zero_out_kernel(float4* __restrict__ p, int n4) {
    const int i = blockIdx.x * blockDim.x + threadIdx.x;
    if (i < n4) p[i] = make_float4(0.f, 0.f, 0.f, 0.f);
}

// WT[k][i] = |W[i][k]|  (R8-proven)
__global__ __launch_bounds__(256)
void transpose_abs_kernel(const float* __restrict__ W, float* __restrict__ WT) {
    __shared__ float S[64][65];
    const int i0 = blockIdx.x * 64;
    const int k0 = blockIdx.y * 64;
    const int tid = threadIdx.x;
#pragma unroll
    for (int w = 0; w < 16; ++w) {
        const int idx = w * 256 + tid;
        const int r = idx >> 6, c = idx & 63;
        if (k0 + c < K) S[r][c] = fabsf(W[(size_t)(i0 + r) * K + k0 + c]);
    }
    __syncthreads();
#pragma unroll
    for (int w = 0; w < 16; ++w) {
        const int idx = w * 256 + tid;
        const int r = idx >> 6, c = idx & 63;
        if (k0 + r < K) WT[(size_t)(k0 + r) * N + i0 + c] = S[c][r];
    }
}

// ---------------- main gram kernel (DMA dbuf path) ----------------
__global__ __launch_bounds__(256, 2)
void gram_dma_kernel(const float* __restrict__ WT, float* __restrict__ H) {
    __shared__ float As[2][BKD][BT];     // 2 x 8 KB
    __shared__ float Bs[2][BKD][BT];     // 2 x 8 KB -> 32 KB/block

    const int tid  = threadIdx.x;
    const int lane = tid & 63;
    const int wid  = tid >> 6;           // 0..3 (wave-uniform)

    // ---- block decode: (tile, split-chunk), 72x8 + 64x7 = 1024
    const int bid = blockIdx.x;
    int tile, kbeg, nstep;
    if (bid < BID8) {
        tile  = bid >> 3;
        kbeg  = (bid & 7) * CH8;
        nstep = NSD8;
    } else {
        const int r = bid - BID8;
        tile  = TILES8 + r / 7;
        kbeg  = (r % 7) * CH7;
        nstep = NSD7;
    }
    int t = tile;
    int bi = 0;
    while (t >= NT - bi) { t -= NT - bi; ++bi; }
    const int bj = bi + t;
    const int i0 = bi * BT, j0 = bj * BT;
    const bool diag = (bi == bj);

    // DMA lane mapping: tile byte = cc*1024 + lane*16
    //   -> k-row = 2*cc + lane/32, col = (lane%32)*4  (k-major [BKD][BT])
    const int krow_off = lane >> 5;      // 0/1
    const int i_off    = (lane & 31) * 4;

    // ---- compute map: four 4x4 sub-tiles at (+0,+64) (R12 verbatim)
    const int tx = tid & 15, ty = tid >> 4;
    const int ra = ty * 4, rb = ra + 64;
    const int ca = tx * 4, cb = ca + 64;

    float acc[8][8];
#pragma unroll
    for (int m = 0; m < 8; ++m)
#pragma unroll
        for (int n = 0; n < 8; ++n) acc[m][n] = 0.0f;   // all sums >= 0

    // ---- DMA stage of step s into buffer nb (8 calls/tile, 2 per wave)
    auto stage = [&](int nb, int s) {
        const int kbase = kbeg + s * BKD;
#pragma unroll
        for (int q = 0; q < 2; ++q) {
            const int cc = wid * 2 + q;              // 0..7 across waves
            int k = kbase + 2 * cc + krow_off;
            if (k > K - 1) k = K - 1;                // same-k dup: legal in max
            gload16(WT + (size_t)k * N + i0 + i_off,
                    (char*)&As[nb][0][0] + cc * 1024);
        }
        if (!diag) {
#pragma unroll
            for (int q = 0; q < 2; ++q) {
                const int cc = wid * 2 + q;
                int k = kbase + 2 * cc + krow_off;
                if (k > K - 1) k = K - 1;
                gload16(WT + (size_t)k * N + j0 + i_off,
                        (char*)&Bs[nb][0][0] + cc * 1024);
            }
        }
    };

    stage(0, 0);
    __syncthreads();                     // vmcnt(0): buffer 0 landed

    for (int s = 0; s < nstep; ++s) {
        const int cur = s & 1;
        if (s + 1 < nstep) stage(cur ^ 1, s + 1);   // DMA rides under compute

        const float (*Acur)[BT] = As[cur];
        const float (*Bcur)[BT] = diag ? As[cur] : Bs[cur];

#pragma unroll 2
        for (int kk = 0; kk < BKD; kk += 2) {
            // fragment reads: stride-16B across lanes -> <=2-way aliasing
            const float4 A0a = *reinterpret_cast<const float4*>(&Acur[kk][ra]);
            const float4 A0b = *reinterpret_cast<const float4*>(&Acur[kk][rb]);
            const float4 A1a = *reinterpret_cast<const float4*>(&Acur[kk + 1][ra]);
            const float4 A1b = *reinterpret_cast<const float4*>(&Acur[kk + 1][rb]);
            const float4 B0a = *reinterpret_cast<const float4*>(&Bcur[kk][ca]);
            const float4 B0b = *reinterpret_cast<const float4*>(&Bcur[kk][cb]);
            const float4 B1a = *reinterpret_cast<const float4*>(&Bcur[kk + 1][ca]);
            const float4 B1b = *reinterpret_cast<const float4*>(&Bcur[kk + 1][cb]);
            const float a0[8] = {A0a.x, A0a.y, A0a.z, A0a.w, A0b.x, A0b.y, A0b.z, A0b.w};
            const float a1[8] = {A1a.x, A1a.y, A1a.z, A1a.w, A1b.x, A1b.y, A1b.z, A1b.w};
            const f32x2 b0p[4] = {{B0a.x, B0a.y}, {B0a.z, B0a.w}, {B0b.x, B0b.y}, {B0b.z, B0b.w}};
            const f32x2 b1p[4] = {{B1a.x, B1a.y}, {B1a.z, B1a.w}, {B1b.x, B1b.y}, {B1b.z, B1b.w}};
#pragma unroll
            for (int m = 0; m < 8; ++m) {
                const f32x2 am0 = {a0[m], a0[m]};
                const f32x2 am1 = {a1[m], a1[m]};
#pragma unroll
                for (int np = 0; np < 4; ++np) {
                    const f32x2 t0 = am0 + b0p[np];     // v_pk_add_f32
                    const f32x2 t1 = am1 + b1p[np];
                    acc[m][2 * np]     = max3f(acc[m][2 * np],     t0.x, t1.x);
                    acc[m][2 * np + 1] = max3f(acc[m][2 * np + 1], t0.y, t1.y);
                }
            }
        }
        // vmcnt(0) (next buffer landed) + lgkmcnt + barrier in one
        __syncthreads();
    }

    // ---- epilogue: canonical orientation; int-bitcast atomicMax merges
    // the K-splits (all values >= 0 -> float order == int order)
    int* Hi = (int*)H;
#pragma unroll
    for (int m = 0; m < 8; ++m) {
        const int r = (m < 4) ? (ra + m) : (rb + m - 4);
#pragma unroll
        for (int n = 0; n < 8; ++n) {
            const int c = (n < 4) ? (ca + n) : (cb + n - 4);
            atomicMax(&Hi[(size_t)(i0 + r) * N + j0 + c], __float_as_int(acc[m][n]));
        }
    }
}

// ---------------- fallback (R12-proven path) ----------------
__global__ __launch_bounds__(256, 2)
void tropical_gram_kernel(const float* __restrict__ W, float* __restrict__ H) {
    __shared__ float As[BK][BT];
    __shared__ float Bs[BK][BT];
    const int tid = threadIdx.x;
    const int bid = blockIdx.x;
    int tile, kbeg, nstep;
    if (bid < BID8) { tile = bid >> 3; kbeg = (bid & 7) * CH8; nstep = NS8; }
    else { const int r = bid - BID8; tile = TILES8 + r / 7; kbeg = (r % 7) * CH7; nstep = NS7; }
    int t = tile; int bi = 0;
    while (t >= NT - bi) { t -= NT - bi; ++bi; }
    const int bj = bi + t;
    const int i0 = bi * BT, j0 = bj * BT;
    const bool diag = (bi == bj);
    const int srow = tid & 127, kh = tid >> 7;
    const float* rowi = W + (size_t)(i0 + srow) * K + kbeg + kh * 16;
    const float* rowj = W + (size_t)(j0 + srow) * K + kbeg + kh * 16;
    const int tx = tid & 15, ty = tid >> 4;
    const int ra = ty * 4, rb = ra + 64, ca = tx * 4, cb = ca + 64;
    float acc[8][8];
#pragma unroll
    for (int m = 0; m < 8; ++m)
#pragma unroll
        for (int n = 0; n < 8; ++n) acc[m][n] = 0.0f;
    float4 va[4], vb[4];
    const float4 z4 = make_float4(0.f, 0.f, 0.f, 0.f);
    auto fetchA = [&](int s) {
#pragma unroll
        for (int qq = 0; qq < 4; ++qq) {
            const int kg = kbeg + kh * 16 + s * BK + qq * 4;
            va[qq] = (kg < K) ? *reinterpret_cast<const float4*>(rowi + s * BK + qq * 4) : z4;
        }
    };
    auto fetchB = [&](int s) {
#pragma unroll
        for (int qq = 0; qq < 4; ++qq) {
            const int kg = kbeg + kh * 16 + s * BK + qq * 4;
            vb[qq] = (kg < K) ? *reinterpret_cast<const float4*>(rowj + s * BK + qq * 4) : z4;
        }
    };
    fetchA(0);
    if (!diag) fetchB(0);
    const float (*Bsrc)[BT] = diag ? As : Bs;
    for (int s = 0; s < nstep; ++s) {
        asm volatile("s_barrier" ::: "memory");
#pragma unroll
        for (int qq = 0; qq < 4; ++qq) {
            const int kb = kh * 16 + qq * 4;
            As[kb + 0][srow] = fabsf(va[qq].x);
            As[kb + 1][srow] = fabsf(va[qq].y);
            As[kb + 2][srow] = fabsf(va[qq].z);
            As[kb + 3][srow] = fabsf(va[qq].w);
        }
        if (!diag) {
#pragma unroll
            for (int qq = 0; qq < 4; ++qq) {
                const int kb = kh * 16 + qq * 4;
                Bs[kb + 0][srow] = fabsf(vb[qq].x);
                Bs[kb + 1][srow] = fabsf(vb[qq].y);
                Bs[kb + 2][srow] = fabsf(vb[qq].z);
                Bs[kb + 3][srow] = fabsf(vb[qq].w);
            }
        }
        if (s + 1 < nstep) { fetchA(s + 1); if (!diag) fetchB(s + 1); }
        asm volatile("s_waitcnt lgkmcnt(0)\n\ts_barrier" ::: "memory");
#pragma unroll 2
        for (int kk = 0; kk < BK; kk += 2) {
            const float4 A0a = *reinterpret_cast<const float4*>(&As[kk][ra]);
            const float4 A0b = *reinterpret_cast<const float4*>(&As[kk][rb]);
            const float4 A1a = *reinterpret_cast<const float4*>(&As[kk + 1][ra]);
            const float4 A1b = *reinterpret_cast<const float4*>(&As[kk + 1][rb]);
            const float4 B0a = *reinterpret_cast<const float4*>(&Bsrc[kk][ca]);
            const float4 B0b = *reinterpret_cast<const float4*>(&Bsrc[kk][cb]);
            const float4 B1a = *reinterpret_cast<const float4*>(&Bsrc[kk + 1][ca]);
            const float4 B1b = *reinterpret_cast<const float4*>(&Bsrc[kk + 1][cb]);
            const float a0[8] = {A0a.x, A0a.y, A0a.z, A0a.w, A0b.x, A0b.y, A0b.z, A0b.w};
            const float a1[8] = {A1a.x, A1a.y, A1a.z, A1a.w, A1b.x, A1b.y, A1b.z, A1b.w};
            const f32x2 b0p[4] = {{B0a.x, B0a.y}, {B0a.z, B0a.w}, {B0b.x, B0b.y}, {B0b.z, B0b.w}};
            const f32x2 b1p[4] = {{B1a.x, B1a.y}, {B1a.z, B1a.w}, {B1b.x, B1b.y}, {B1b.z, B1b.w}};
#pragma unroll
            for (int m = 0; m < 8; ++m) {
                const f32x2 am0 = {a0[m], a0[m]};
                const f32x2 am1 = {a1[m], a1[m]};
#pragma unroll
                for (int np = 0; np < 4; ++np) {
                    const f32x2 t0 = am0 + b0p[np];
                    const f32x2 t1 = am1 + b1p[np];
                    acc[m][2 * np]     = max3f(acc[m][2 * np],     t0.x, t1.x);
                    acc[m][2 * np + 1] = max3f(acc[m][2 * np + 1], t0.y, t1.y);
                }
            }
        }
    }
    int* Hi = (int*)H;
#pragma unroll
    for (int m = 0; m < 8; ++m) {
        const int r = (m < 4) ? (ra + m) : (rb + m - 4);
#pragma unroll
        for (int n = 0; n < 8; ++n) {
            const int c = (n < 4) ? (ca + n) : (cb + n - 4);
            atomicMax(&Hi[(size_t)(i0 + r) * N + j0 + c], __float_as_int(acc[m][n]));
        }
    }
}

// fill strictly-lower 64-tiles from the upper triangle (H[j][i] = H[i][j])
constexpr int MT = 64;
constexpr int NT64 = N / MT;                 // 32
constexpr int NMIR = NT64 * (NT64 - 1) / 2;  // 496

__global__ __launch_bounds__(256)
void mirror_kernel(float* __restrict__ H) {
    __shared__ float S[MT][MT + 1];
    int t = blockIdx.x;
    int ti = 0;
    while (t >= NT64 - 1 - ti) { t -= NT64 - 1 - ti; ++ti; }
    const int tj = ti + 1 + t;
    const int r0 = ti * MT, c0 = tj * MT;
    const int tid = threadIdx.x;
#pragma unroll
    for (int w = 0; w < 16; ++w) {
        const int idx = w * 256 + tid;
        const int r = idx >> 6, c = idx & 63;
        S[r][c] = H[(size_t)(r0 + r) * N + c0 + c];
    }
    __syncthreads();
#pragma unroll
    for (int w = 0; w < 16; ++w) {
        const int idx = w * 256 + tid;
        const int r = idx >> 6, c = idx & 63;
        H[(size_t)(c0 + r) * N + r0 + c] = S[c][r];
    }
}

extern "C" void kernel_launch(void* const* d_in, const int* in_sizes, int n_in,
                              void* d_out, int out_size, void* d_ws, size_t ws_size,
                              hipStream_t stream) {
    const float* W = (const float*)d_in[0];
    float* H = (float*)d_out;
    (void)in_sizes; (void)n_in; (void)out_size;

    const int n4 = N * N / 4;
    zero_out_kernel<<<(n4 + 255) / 256, 256, 0, stream>>>((float4*)H, n4);

    if (ws_size >= WT_BYTES) {
        float* WT = (float*)d_ws;
        transpose_abs_kernel<<<dim3(N / 64, (K + 63) / 64), dim3(256), 0, stream>>>(W, WT);
        gram_dma_kernel<<<dim3(1024), dim3(256), 0, stream>>>(WT, H);
    } else {
        tropical_gram_kernel<<<dim3(1024), dim3(256), 0, stream>>>(W, H);
    }
    mirror_kernel<<<dim3(NMIR), dim3(256), 0, stream>>>(H);
}